// Round 1
// baseline (336.634 us; speedup 1.0000x reference)
//
#include <hip/hip_runtime.h>
#include <hip/hip_bf16.h>
#include <math.h>

// Problem constants
#define FDIM 6272
#define LQ   256
#define BN   8
#define UDIM 32
#define BL   (BN*LQ)        // 2048
#define F4   (FDIM/4)       // 1568
#define K1_SPLIT 4
#define K1_SEG  (FDIM/K1_SPLIT)  // 1568

// ---------------------------------------------------------------------------
// K1: pb[row][u] = sum_f x[row][f] * Wt[f][u]   (K-split x4, fp32 atomics)
// grid: (BL/8, K1_SPLIT), block: 256 = 8 rows x 32 u
// ---------------------------------------------------------------------------
__global__ void k1_proj(const float* __restrict__ x, const float* __restrict__ Wt,
                        float* __restrict__ pb) {
    const int u   = threadIdx.x & 31;
    const int rl  = threadIdx.x >> 5;            // 0..7
    const int row = blockIdx.x * 8 + rl;         // 0..2047
    const int f0  = blockIdx.y * K1_SEG;

    const float* xr = x + (size_t)row * FDIM + f0;
    const float* w  = Wt + (size_t)f0 * UDIM + u;

    float acc = 0.f;
    for (int i = 0; i < K1_SEG; i += 4) {
        const float4 xv = *(const float4*)(xr + i);
        acc = fmaf(xv.x, w[(i + 0) * UDIM], acc);
        acc = fmaf(xv.y, w[(i + 1) * UDIM], acc);
        acc = fmaf(xv.z, w[(i + 2) * UDIM], acc);
        acc = fmaf(xv.w, w[(i + 3) * UDIM], acc);
    }
    atomicAdd(&pb[row * UDIM + u], acc);
}

// ---------------------------------------------------------------------------
// K2: alpha[b,q,k] = sigmoid( sum_u tanh(p[b,q,u] + p[b,k,u] + bh[u]) * Wa[u] + ba )
//     a[b,q,:] = softmax_k(alpha)
// grid: BL blocks (one per (b,q)), block: 256 threads (one per k)
// ---------------------------------------------------------------------------
__global__ void k2_attn(const float* __restrict__ pb, const float* __restrict__ bh,
                        const float* __restrict__ Wa, const float* __restrict__ ba,
                        float* __restrict__ a) {
    const int bq = blockIdx.x;    // b*256 + q
    const int b  = bq >> 8;
    const int k  = threadIdx.x;   // 0..255

    __shared__ float pq_s[UDIM];
    __shared__ float wa_s[UDIM];
    __shared__ float pk_s[LQ * 33];   // pad 33: bank = (k+u)%32 -> 2-way (free)
    __shared__ float red[4];

    if (k < UDIM) {
        pq_s[k] = pb[bq * UDIM + k] + bh[k];
        wa_s[k] = Wa[k];
    }
    const float* pbb = pb + (size_t)b * LQ * UDIM;
    #pragma unroll
    for (int i = 0; i < 32; ++i) {
        int idx = k + i * 256;    // 0..8191, coalesced global read
        pk_s[(idx >> 5) * 33 + (idx & 31)] = pbb[idx];
    }
    __syncthreads();

    const float* pk = &pk_s[k * 33];
    float s = 0.f;
    #pragma unroll
    for (int u = 0; u < UDIM; ++u)
        s = fmaf(tanhf(pq_s[u] + pk[u]), wa_s[u], s);

    const float alpha = 1.f / (1.f + expf(-(s + ba[0])));
    // softmax over k: sigmoid output in (0,1) -> exp safe without max-sub
    const float e = expf(alpha);

    float v = e;
    #pragma unroll
    for (int m = 1; m < 64; m <<= 1) v += __shfl_xor(v, m, 64);
    if ((k & 63) == 0) red[k >> 6] = v;
    __syncthreads();
    const float tot = red[0] + red[1] + red[2] + red[3];

    a[(size_t)bq * LQ + k] = e / tot;
}

// ---------------------------------------------------------------------------
// K3: out[b,q,f] = sum_k a[b,q,k] * x[b,k,f]
// grid: (ceil(F4/256)=7, 256/32=8, BN), block: 256 threads (one float4 of f each)
// Each block: 32 q-rows x 1024 f-columns. a-tile (32KB) staged in LDS,
// read as broadcast float4 (no bank conflicts). acc = 32 float4 = 128 VGPR.
// ---------------------------------------------------------------------------
__global__ __launch_bounds__(256, 2)
void k3_ctx(const float* __restrict__ x, const float* __restrict__ a,
            float* __restrict__ out) {
    const int tid = threadIdx.x;
    const int f4  = blockIdx.x * 256 + tid;      // float4 column index
    const int q0  = blockIdx.y * 32;
    const int b   = blockIdx.z;

    __shared__ float4 a_s[32 * 64];              // [q_local][k4] = 32KB

    const float4* ag = (const float4*)(a + ((size_t)b * LQ + q0) * LQ);
    #pragma unroll
    for (int i = 0; i < 8; ++i) a_s[tid + i * 256] = ag[tid + i * 256];
    __syncthreads();

    const bool ok = (f4 < F4);
    const int f4c = ok ? f4 : 0;                 // clamp: always-safe loads
    const float4* x4 = (const float4*)(x + (size_t)b * LQ * FDIM);

    float4 acc[32];
    #pragma unroll
    for (int j = 0; j < 32; ++j) acc[j] = make_float4(0.f, 0.f, 0.f, 0.f);

    for (int k4 = 0; k4 < 64; ++k4) {
        const float4 xv0 = x4[(size_t)(k4 * 4 + 0) * F4 + f4c];
        const float4 xv1 = x4[(size_t)(k4 * 4 + 1) * F4 + f4c];
        const float4 xv2 = x4[(size_t)(k4 * 4 + 2) * F4 + f4c];
        const float4 xv3 = x4[(size_t)(k4 * 4 + 3) * F4 + f4c];
        #pragma unroll
        for (int j = 0; j < 32; ++j) {
            const float4 av = a_s[j * 64 + k4];
            acc[j].x = fmaf(av.x, xv0.x, acc[j].x);
            acc[j].y = fmaf(av.x, xv0.y, acc[j].y);
            acc[j].z = fmaf(av.x, xv0.z, acc[j].z);
            acc[j].w = fmaf(av.x, xv0.w, acc[j].w);
            acc[j].x = fmaf(av.y, xv1.x, acc[j].x);
            acc[j].y = fmaf(av.y, xv1.y, acc[j].y);
            acc[j].z = fmaf(av.y, xv1.z, acc[j].z);
            acc[j].w = fmaf(av.y, xv1.w, acc[j].w);
            acc[j].x = fmaf(av.z, xv2.x, acc[j].x);
            acc[j].y = fmaf(av.z, xv2.y, acc[j].y);
            acc[j].z = fmaf(av.z, xv2.z, acc[j].z);
            acc[j].w = fmaf(av.z, xv2.w, acc[j].w);
            acc[j].x = fmaf(av.w, xv3.x, acc[j].x);
            acc[j].y = fmaf(av.w, xv3.y, acc[j].y);
            acc[j].z = fmaf(av.w, xv3.z, acc[j].z);
            acc[j].w = fmaf(av.w, xv3.w, acc[j].w);
        }
    }

    if (ok) {
        float4* o4 = (float4*)out;
        #pragma unroll
        for (int j = 0; j < 32; ++j)
            o4[(size_t)(b * LQ + q0 + j) * F4 + f4] = acc[j];
    }
}

// ---------------------------------------------------------------------------
extern "C" void kernel_launch(void* const* d_in, const int* in_sizes, int n_in,
                              void* d_out, int out_size, void* d_ws, size_t ws_size,
                              hipStream_t stream) {
    const float* x  = (const float*)d_in[0];   // [8,256,6272]
    const float* Wt = (const float*)d_in[1];   // [6272,32]
    const float* bh = (const float*)d_in[2];   // [32]
    const float* Wa = (const float*)d_in[3];   // [32,1]
    const float* ba = (const float*)d_in[4];   // [1]
    float* out = (float*)d_out;                // [8,256,6272]

    float* pb = (float*)d_ws;                  // [2048,32] fp32 (256KB)
    float* a  = pb + BL * UDIM;                // [8,256,256] fp32 (2MB)

    // zero the atomic accumulation buffer
    hipMemsetAsync(pb, 0, (size_t)BL * UDIM * sizeof(float), stream);

    dim3 g1(BL / 8, K1_SPLIT);
    k1_proj<<<g1, 256, 0, stream>>>(x, Wt, pb);

    k2_attn<<<BL, 256, 0, stream>>>(pb, bh, Wa, ba, a);

    dim3 g3((F4 + 255) / 256, LQ / 32, BN);
    k3_ctx<<<g3, 256, 0, stream>>>(x, a, out);
}

// Round 2
// 214.754 us; speedup vs baseline: 1.5675x; 1.5675x over previous
//
#include <hip/hip_runtime.h>
#include <hip/hip_bf16.h>
#include <math.h>

#define FDIM 6272
#define LQ   256
#define BN   8
#define UDIM 32
#define BL   (BN*LQ)        // 2048

typedef short  short8 __attribute__((ext_vector_type(8)));
typedef float  f32x4  __attribute__((ext_vector_type(4)));

static __device__ __forceinline__ ushort f2bf(float f) {
    __hip_bfloat16 h = __float2bfloat16(f);
    return *(ushort*)&h;
}

// ---------------------------------------------------------------------------
// K0: x[b][k][f] fp32 -> x_t[b][f][k] bf16, via LDS transpose.
// grid (98 f-tiles, 4 k-tiles, 8 b), block 256. Tile 64k x 64f.
// LDS layout: xt_s[f][kpair] words, row stride 33 (pad) -> 2-way banks (free).
// ---------------------------------------------------------------------------
__global__ __launch_bounds__(256)
void k0_transpose(const float* __restrict__ x, ushort* __restrict__ xt) {
    __shared__ unsigned int xt_s[64 * 33];
    const int t  = threadIdx.x;
    const int f0 = blockIdx.x * 64, k0 = blockIdx.y * 64, b = blockIdx.z;

    const int f4 = t & 15, kr = t >> 4;     // 16 f-quads x 16 kpair-slots
    const float* xb = x + ((size_t)b * LQ + k0) * FDIM + f0;

    #pragma unroll
    for (int i = 0; i < 2; ++i) {
        const int kp = kr + 16 * i;         // k-pair 0..31
        const float4 v0 = *(const float4*)(xb + (size_t)(2 * kp    ) * FDIM + 4 * f4);
        const float4 v1 = *(const float4*)(xb + (size_t)(2 * kp + 1) * FDIM + 4 * f4);
        xt_s[(4 * f4 + 0) * 33 + kp] = (unsigned)f2bf(v0.x) | ((unsigned)f2bf(v1.x) << 16);
        xt_s[(4 * f4 + 1) * 33 + kp] = (unsigned)f2bf(v0.y) | ((unsigned)f2bf(v1.y) << 16);
        xt_s[(4 * f4 + 2) * 33 + kp] = (unsigned)f2bf(v0.z) | ((unsigned)f2bf(v1.z) << 16);
        xt_s[(4 * f4 + 3) * 33 + kp] = (unsigned)f2bf(v0.w) | ((unsigned)f2bf(v1.w) << 16);
    }
    __syncthreads();

    // write out: 8 threads per f-row x 16B each -> 128B contiguous per row
    const int kc8 = t & 7;
    #pragma unroll
    for (int p = 0; p < 2; ++p) {
        const int fr = (t >> 3) + 32 * p;
        uint4 pkt;
        pkt.x = xt_s[fr * 33 + kc8 * 4 + 0];
        pkt.y = xt_s[fr * 33 + kc8 * 4 + 1];
        pkt.z = xt_s[fr * 33 + kc8 * 4 + 2];
        pkt.w = xt_s[fr * 33 + kc8 * 4 + 3];
        *(uint4*)(xt + ((size_t)b * FDIM + f0 + fr) * LQ + k0 + kc8 * 8) = pkt;
    }
}

// ---------------------------------------------------------------------------
// K1: pb[row][u] = sum_f x[row][f] * Wt[f][u]
// thread = (row, u-quad): Wt as float4 (128B coalesced per 8 lanes), x float4.
// grid (64 row-tiles, 16 f-splits), block 256 = 32 rows x 8 u-quads.
// ---------------------------------------------------------------------------
__global__ __launch_bounds__(256)
void k1_proj(const float* __restrict__ x, const float* __restrict__ Wt,
             float* __restrict__ pb) {
    const int t   = threadIdx.x;
    const int u4  = t & 7, rl = t >> 3;
    const int row = blockIdx.x * 32 + rl;
    const int f0  = blockIdx.y * 392;

    const float* xr = x  + (size_t)row * FDIM + f0;
    const float* wp = Wt + (size_t)f0 * UDIM + u4 * 4;

    float4 acc = make_float4(0.f, 0.f, 0.f, 0.f);
    for (int i = 0; i < 98; ++i) {
        const float4 xv = *(const float4*)(xr + 4 * i);
        const float4 w0 = *(const float4*)(wp + (size_t)(4 * i + 0) * UDIM);
        const float4 w1 = *(const float4*)(wp + (size_t)(4 * i + 1) * UDIM);
        const float4 w2 = *(const float4*)(wp + (size_t)(4 * i + 2) * UDIM);
        const float4 w3 = *(const float4*)(wp + (size_t)(4 * i + 3) * UDIM);
        acc.x = fmaf(xv.x, w0.x, acc.x); acc.y = fmaf(xv.x, w0.y, acc.y);
        acc.z = fmaf(xv.x, w0.z, acc.z); acc.w = fmaf(xv.x, w0.w, acc.w);
        acc.x = fmaf(xv.y, w1.x, acc.x); acc.y = fmaf(xv.y, w1.y, acc.y);
        acc.z = fmaf(xv.y, w1.z, acc.z); acc.w = fmaf(xv.y, w1.w, acc.w);
        acc.x = fmaf(xv.z, w2.x, acc.x); acc.y = fmaf(xv.z, w2.y, acc.y);
        acc.z = fmaf(xv.z, w2.z, acc.z); acc.w = fmaf(xv.z, w2.w, acc.w);
        acc.x = fmaf(xv.w, w3.x, acc.x); acc.y = fmaf(xv.w, w3.y, acc.y);
        acc.z = fmaf(xv.w, w3.z, acc.z); acc.w = fmaf(xv.w, w3.w, acc.w);
    }
    float* dst = pb + row * UDIM + u4 * 4;
    atomicAdd(dst + 0, acc.x);
    atomicAdd(dst + 1, acc.y);
    atomicAdd(dst + 2, acc.z);
    atomicAdd(dst + 3, acc.w);
}

// ---------------------------------------------------------------------------
// K2: a[b,q,:] = softmax_k sigmoid( tanh(p_q + p_k + bh) . Wa + ba ), emit bf16
// grid BL, block 256 (one thread per k)
// ---------------------------------------------------------------------------
__global__ __launch_bounds__(256)
void k2_attn(const float* __restrict__ pb, const float* __restrict__ bh,
             const float* __restrict__ Wa, const float* __restrict__ ba,
             ushort* __restrict__ ab) {
    const int bq = blockIdx.x;
    const int b  = bq >> 8;
    const int k  = threadIdx.x;

    __shared__ float pq_s[UDIM];
    __shared__ float wa_s[UDIM];
    __shared__ float pk_s[LQ * 33];
    __shared__ float red[4];

    if (k < UDIM) {
        pq_s[k] = pb[bq * UDIM + k] + bh[k];
        wa_s[k] = Wa[k];
    }
    const float* pbb = pb + (size_t)b * LQ * UDIM;
    #pragma unroll
    for (int i = 0; i < 32; ++i) {
        int idx = k + i * 256;
        pk_s[(idx >> 5) * 33 + (idx & 31)] = pbb[idx];
    }
    __syncthreads();

    const float* pk = &pk_s[k * 33];
    float s = 0.f;
    #pragma unroll
    for (int u = 0; u < UDIM; ++u)
        s = fmaf(tanhf(pq_s[u] + pk[u]), wa_s[u], s);

    const float alpha = 1.f / (1.f + expf(-(s + ba[0])));
    const float e = expf(alpha);          // sigmoid output in (0,1): exp safe

    float v = e;
    #pragma unroll
    for (int m = 1; m < 64; m <<= 1) v += __shfl_xor(v, m, 64);
    if ((k & 63) == 0) red[k >> 6] = v;
    __syncthreads();
    const float tot = red[0] + red[1] + red[2] + red[3];

    ab[(size_t)bq * LQ + k] = f2bf(e / tot);
}

// ---------------------------------------------------------------------------
// K3: out[b,q,f] = sum_k a[b,q,k] * x[b,k,f]  via bf16 MFMA 16x16x32.
// A-operand = a (q x k, k-contig), B-operand = x_t rows (f x k, k-contig).
// Block: 64q x 128f, K-loop BK=64 x 4. LDS rows padded to 72 bf16
// (144 B = 9x16B units, odd -> conflict-free ds_read_b128 frags).
// grid (49 f-tiles, 4 q-tiles, 8 b), block 256 = 4 waves (one 16q band each).
// ---------------------------------------------------------------------------
__global__ __launch_bounds__(256)
void k3_mfma(const ushort* __restrict__ xt, const ushort* __restrict__ ab,
             float* __restrict__ out) {
    __shared__ ushort xs[128 * 72];   // 18 KB
    __shared__ ushort as_[64 * 72];   //  9 KB

    const int t    = threadIdx.x;
    const int f0   = blockIdx.x * 128, q0 = blockIdx.y * 64, b = blockIdx.z;
    const int wv   = t >> 6;
    const int lane = t & 63;
    const int n    = lane & 15;       // = m for A-operand, = col for B/C
    const int quad = lane >> 4;

    const ushort* xtb = xt + ((size_t)b * FDIM + f0) * LQ;
    const ushort* abb = ab + ((size_t)b * LQ + q0) * LQ;

    f32x4 acc[8];
    #pragma unroll
    for (int ff = 0; ff < 8; ++ff) acc[ff] = (f32x4){0.f, 0.f, 0.f, 0.f};

    for (int c = 0; c < 4; ++c) {
        const int kk = c * 64;
        __syncthreads();              // prev chunk's frag reads done
        // stage xs: 128 rows x 64k bf16 (1024 16B units), coalesced 128B/row
        #pragma unroll
        for (int j = 0; j < 4; ++j) {
            const int g = t + 256 * j;
            const int r = g >> 3, c8 = g & 7;
            const uint4 v = *(const uint4*)(xtb + (size_t)r * LQ + kk + c8 * 8);
            *(uint4*)(xs + r * 72 + c8 * 8) = v;
        }
        // stage as_: 64 rows x 64k (512 units)
        #pragma unroll
        for (int j = 0; j < 2; ++j) {
            const int g = t + 256 * j;
            const int r = g >> 3, c8 = g & 7;
            const uint4 v = *(const uint4*)(abb + (size_t)r * LQ + kk + c8 * 8);
            *(uint4*)(as_ + r * 72 + c8 * 8) = v;
        }
        __syncthreads();

        #pragma unroll
        for (int ks = 0; ks < 64; ks += 32) {
            const short8 af = *(const short8*)(as_ + (16 * wv + n) * 72 + ks + quad * 8);
            #pragma unroll
            for (int ff = 0; ff < 8; ++ff) {
                const short8 bfr = *(const short8*)(xs + (16 * ff + n) * 72 + ks + quad * 8);
                acc[ff] = __builtin_amdgcn_mfma_f32_16x16x32_bf16(af, bfr, acc[ff], 0, 0, 0);
            }
        }
    }

    // epilogue: C row = q0+16*wv+quad*4+r, col = f0+16*ff+n
    float* ob = out + ((size_t)b * LQ + q0 + 16 * wv + quad * 4) * FDIM + f0 + n;
    #pragma unroll
    for (int ff = 0; ff < 8; ++ff)
        #pragma unroll
        for (int r = 0; r < 4; ++r)
            ob[(size_t)r * FDIM + 16 * ff] = acc[ff][r];
}

// ---------------------------------------------------------------------------
extern "C" void kernel_launch(void* const* d_in, const int* in_sizes, int n_in,
                              void* d_out, int out_size, void* d_ws, size_t ws_size,
                              hipStream_t stream) {
    const float* x  = (const float*)d_in[0];   // [8,256,6272]
    const float* Wt = (const float*)d_in[1];   // [6272,32]
    const float* bh = (const float*)d_in[2];   // [32]
    const float* Wa = (const float*)d_in[3];   // [32,1]
    const float* ba = (const float*)d_in[4];   // [1]
    float* out = (float*)d_out;                // [8,256,6272]

    // workspace layout (16B aligned segments)
    float*  pb = (float*)d_ws;                                  // 2048*32 fp32   (256 KB)
    ushort* ab = (ushort*)((char*)d_ws + 262144);               // 8*256*256 bf16 (1 MB)
    ushort* xt = (ushort*)((char*)d_ws + 262144 + 1048576);     // 8*6272*256 bf16 (25.7 MB)

    hipMemsetAsync(pb, 0, (size_t)BL * UDIM * sizeof(float), stream);

    k0_transpose<<<dim3(98, 4, 8), 256, 0, stream>>>(x, xt);
    k1_proj<<<dim3(64, 16), 256, 0, stream>>>(x, Wt, pb);
    k2_attn<<<BL, 256, 0, stream>>>(pb, bh, Wa, ba, ab);
    k3_mfma<<<dim3(49, 4, 8), 256, 0, stream>>>(xt, ab, out);
}

// Round 3
// 165.937 us; speedup vs baseline: 2.0287x; 1.2942x over previous
//
#include <hip/hip_runtime.h>
#include <hip/hip_bf16.h>
#include <math.h>

#define FDIM 6272
#define LQ   256
#define BN   8
#define UDIM 32
#define BL   (BN*LQ)        // 2048

typedef short  short8 __attribute__((ext_vector_type(8)));
typedef float  f32x4  __attribute__((ext_vector_type(4)));

static __device__ __forceinline__ ushort f2bf(float f) {
    __hip_bfloat16 h = __float2bfloat16(f);
    return *(ushort*)&h;
}

// ---------------------------------------------------------------------------
// K0: x[b][k][f] fp32 -> x_t[b][f][k] bf16, via LDS transpose.
// grid (98 f-tiles, 4 k-tiles, 8 b), block 256. Tile 64k x 64f.
// ---------------------------------------------------------------------------
__global__ __launch_bounds__(256)
void k0_transpose(const float* __restrict__ x, ushort* __restrict__ xt) {
    __shared__ unsigned int xt_s[64 * 33];
    const int t  = threadIdx.x;
    const int f0 = blockIdx.x * 64, k0 = blockIdx.y * 64, b = blockIdx.z;

    const int f4 = t & 15, kr = t >> 4;     // 16 f-quads x 16 kpair-slots
    const float* xb = x + ((size_t)b * LQ + k0) * FDIM + f0;

    #pragma unroll
    for (int i = 0; i < 2; ++i) {
        const int kp = kr + 16 * i;         // k-pair 0..31
        const float4 v0 = *(const float4*)(xb + (size_t)(2 * kp    ) * FDIM + 4 * f4);
        const float4 v1 = *(const float4*)(xb + (size_t)(2 * kp + 1) * FDIM + 4 * f4);
        xt_s[(4 * f4 + 0) * 33 + kp] = (unsigned)f2bf(v0.x) | ((unsigned)f2bf(v1.x) << 16);
        xt_s[(4 * f4 + 1) * 33 + kp] = (unsigned)f2bf(v0.y) | ((unsigned)f2bf(v1.y) << 16);
        xt_s[(4 * f4 + 2) * 33 + kp] = (unsigned)f2bf(v0.z) | ((unsigned)f2bf(v1.z) << 16);
        xt_s[(4 * f4 + 3) * 33 + kp] = (unsigned)f2bf(v0.w) | ((unsigned)f2bf(v1.w) << 16);
    }
    __syncthreads();

    const int kc8 = t & 7;
    #pragma unroll
    for (int p = 0; p < 2; ++p) {
        const int fr = (t >> 3) + 32 * p;
        uint4 pkt;
        pkt.x = xt_s[fr * 33 + kc8 * 4 + 0];
        pkt.y = xt_s[fr * 33 + kc8 * 4 + 1];
        pkt.z = xt_s[fr * 33 + kc8 * 4 + 2];
        pkt.w = xt_s[fr * 33 + kc8 * 4 + 3];
        *(uint4*)(xt + ((size_t)b * FDIM + f0 + fr) * LQ + k0 + kc8 * 8) = pkt;
    }
}

// ---------------------------------------------------------------------------
// Kw: Wtt[u][f] = bf16(Wt[f][u])  (802KB -> 400KB, one-shot, L2-resident)
// grid 98 x 256: thread handles one u, 8 consecutive f (coalesced 16B writes)
// ---------------------------------------------------------------------------
__global__ __launch_bounds__(256)
void k_wtt(const float* __restrict__ Wt, ushort* __restrict__ wtt) {
    const int gid = blockIdx.x * 256 + threadIdx.x;   // 0..25087
    const int u = gid / 784, fg = gid % 784;
    ushort v[8];
    #pragma unroll
    for (int j = 0; j < 8; ++j)
        v[j] = f2bf(Wt[(size_t)(8 * fg + j) * UDIM + u]);
    *(uint4*)(wtt + (size_t)u * FDIM + 8 * fg) = *(uint4*)v;
}

// ---------------------------------------------------------------------------
// K1: pb[row][u] = sum_f x[row][f] * Wt[f][u]  via bf16 MFMA 16x16x32.
// Block: 32 rows x 32 u, K-range 896 (f-split 7), BK=32 -> 28 chunks.
// 4 waves: wave w does (m-half w&1, n-half w>>1), 1 MFMA/chunk.
// LDS rows stride 40 ushorts (80B = 5x16B units, odd -> <=2-way banks, free).
// fp32 atomicAdd epilogue (7 partials per dest).
// grid (64 row-tiles, 7 f-splits), block 256.
// ---------------------------------------------------------------------------
__global__ __launch_bounds__(256)
void k1_mfma(const float* __restrict__ x, const ushort* __restrict__ wtt,
             float* __restrict__ pb) {
    __shared__ ushort As[32 * 40];   // 2.5 KB
    __shared__ ushort Bs[32 * 40];   // 2.5 KB

    const int t    = threadIdx.x;
    const int row0 = blockIdx.x * 32;
    const int f0   = blockIdx.y * 896;
    const int wv   = t >> 6, lane = t & 63;
    const int n16  = lane & 15, quad = lane >> 4;
    const int m0   = 16 * (wv & 1), n0 = 16 * (wv >> 1);

    const int srow = t >> 3, sg = t & 7;   // staging: row 0..31, f-group 0..7

    f32x4 acc = (f32x4){0.f, 0.f, 0.f, 0.f};

    for (int c = 0; c < 28; ++c) {
        const int kk = f0 + c * 32;
        __syncthreads();
        // A: x[row0+srow][kk+4sg .. +3] fp32 -> bf16 (8 lanes x 16B = 128B/row)
        const float4 xv = *(const float4*)(x + (size_t)(row0 + srow) * FDIM + kk + 4 * sg);
        uint2 pk;
        pk.x = (unsigned)f2bf(xv.x) | ((unsigned)f2bf(xv.y) << 16);
        pk.y = (unsigned)f2bf(xv.z) | ((unsigned)f2bf(xv.w) << 16);
        *(uint2*)(As + srow * 40 + 4 * sg) = pk;
        // B: Wtt[srow(=u)][kk+4sg .. +3] bf16 direct (8B/lane)
        *(uint2*)(Bs + srow * 40 + 4 * sg) =
            *(const uint2*)(wtt + (size_t)srow * FDIM + kk + 4 * sg);
        __syncthreads();

        const short8 af = *(const short8*)(As + (m0 + n16) * 40 + quad * 8);
        const short8 bf = *(const short8*)(Bs + (n0 + n16) * 40 + quad * 8);
        acc = __builtin_amdgcn_mfma_f32_16x16x32_bf16(af, bf, acc, 0, 0, 0);
    }

    // C layout: col(u) = n0+n16, row = m0+quad*4+r
    #pragma unroll
    for (int r = 0; r < 4; ++r)
        atomicAdd(&pb[(size_t)(row0 + m0 + quad * 4 + r) * UDIM + n0 + n16], acc[r]);
}

// ---------------------------------------------------------------------------
// K2: a[b,q,:] = softmax_k sigmoid( tanh(p_q + p_k + bh) . Wa + ba ), emit bf16
// ---------------------------------------------------------------------------
__global__ __launch_bounds__(256)
void k2_attn(const float* __restrict__ pb, const float* __restrict__ bh,
             const float* __restrict__ Wa, const float* __restrict__ ba,
             ushort* __restrict__ ab) {
    const int bq = blockIdx.x;
    const int b  = bq >> 8;
    const int k  = threadIdx.x;

    __shared__ float pq_s[UDIM];
    __shared__ float wa_s[UDIM];
    __shared__ float pk_s[LQ * 33];
    __shared__ float red[4];

    if (k < UDIM) {
        pq_s[k] = pb[bq * UDIM + k] + bh[k];
        wa_s[k] = Wa[k];
    }
    const float* pbb = pb + (size_t)b * LQ * UDIM;
    #pragma unroll
    for (int i = 0; i < 32; ++i) {
        int idx = k + i * 256;
        pk_s[(idx >> 5) * 33 + (idx & 31)] = pbb[idx];
    }
    __syncthreads();

    const float* pk = &pk_s[k * 33];
    float s = 0.f;
    #pragma unroll
    for (int u = 0; u < UDIM; ++u)
        s = fmaf(tanhf(pq_s[u] + pk[u]), wa_s[u], s);

    const float alpha = 1.f / (1.f + expf(-(s + ba[0])));
    const float e = expf(alpha);          // sigmoid output in (0,1): exp safe

    float v = e;
    #pragma unroll
    for (int m = 1; m < 64; m <<= 1) v += __shfl_xor(v, m, 64);
    if ((k & 63) == 0) red[k >> 6] = v;
    __syncthreads();
    const float tot = red[0] + red[1] + red[2] + red[3];

    ab[(size_t)bq * LQ + k] = f2bf(e / tot);
}

// ---------------------------------------------------------------------------
// K3: out[b,q,f] = sum_k a[b,q,k] * x[b,k,f]  via bf16 MFMA 16x16x32.
// grid (49 f-tiles, 4 q-tiles, 8 b), block 256 = 4 waves.
// ---------------------------------------------------------------------------
__global__ __launch_bounds__(256)
void k3_mfma(const ushort* __restrict__ xt, const ushort* __restrict__ ab,
             float* __restrict__ out) {
    __shared__ ushort xs[128 * 72];   // 18 KB
    __shared__ ushort as_[64 * 72];   //  9 KB

    const int t    = threadIdx.x;
    const int f0   = blockIdx.x * 128, q0 = blockIdx.y * 64, b = blockIdx.z;
    const int wv   = t >> 6;
    const int lane = t & 63;
    const int n    = lane & 15;
    const int quad = lane >> 4;

    const ushort* xtb = xt + ((size_t)b * FDIM + f0) * LQ;
    const ushort* abb = ab + ((size_t)b * LQ + q0) * LQ;

    f32x4 acc[8];
    #pragma unroll
    for (int ff = 0; ff < 8; ++ff) acc[ff] = (f32x4){0.f, 0.f, 0.f, 0.f};

    for (int c = 0; c < 4; ++c) {
        const int kk = c * 64;
        __syncthreads();
        #pragma unroll
        for (int j = 0; j < 4; ++j) {
            const int g = t + 256 * j;
            const int r = g >> 3, c8 = g & 7;
            const uint4 v = *(const uint4*)(xtb + (size_t)r * LQ + kk + c8 * 8);
            *(uint4*)(xs + r * 72 + c8 * 8) = v;
        }
        #pragma unroll
        for (int j = 0; j < 2; ++j) {
            const int g = t + 256 * j;
            const int r = g >> 3, c8 = g & 7;
            const uint4 v = *(const uint4*)(abb + (size_t)r * LQ + kk + c8 * 8);
            *(uint4*)(as_ + r * 72 + c8 * 8) = v;
        }
        __syncthreads();

        #pragma unroll
        for (int ks = 0; ks < 64; ks += 32) {
            const short8 af = *(const short8*)(as_ + (16 * wv + n) * 72 + ks + quad * 8);
            #pragma unroll
            for (int ff = 0; ff < 8; ++ff) {
                const short8 bfr = *(const short8*)(xs + (16 * ff + n) * 72 + ks + quad * 8);
                acc[ff] = __builtin_amdgcn_mfma_f32_16x16x32_bf16(af, bfr, acc[ff], 0, 0, 0);
            }
        }
    }

    float* ob = out + ((size_t)b * LQ + q0 + 16 * wv + quad * 4) * FDIM + f0 + n;
    #pragma unroll
    for (int ff = 0; ff < 8; ++ff)
        #pragma unroll
        for (int r = 0; r < 4; ++r)
            ob[(size_t)r * FDIM + 16 * ff] = acc[ff][r];
}

// ---------------------------------------------------------------------------
extern "C" void kernel_launch(void* const* d_in, const int* in_sizes, int n_in,
                              void* d_out, int out_size, void* d_ws, size_t ws_size,
                              hipStream_t stream) {
    const float* x  = (const float*)d_in[0];   // [8,256,6272]
    const float* Wt = (const float*)d_in[1];   // [6272,32]
    const float* bh = (const float*)d_in[2];   // [32]
    const float* Wa = (const float*)d_in[3];   // [32,1]
    const float* ba = (const float*)d_in[4];   // [1]
    float* out = (float*)d_out;                // [8,256,6272]

    // workspace layout (16B aligned segments)
    float*  pb  = (float*)d_ws;                                   // 2048*32 fp32   (256 KB)
    ushort* ab  = (ushort*)((char*)d_ws + 262144);                // 8*256*256 bf16 (1 MB)
    ushort* wtt = (ushort*)((char*)d_ws + 262144 + 1048576);      // 32*6272 bf16   (400 KB)
    ushort* xt  = (ushort*)((char*)d_ws + 262144 + 1048576 + 524288); // 8*6272*256 bf16 (25.7 MB)

    hipMemsetAsync(pb, 0, (size_t)BL * UDIM * sizeof(float), stream);

    k0_transpose<<<dim3(98, 4, 8), 256, 0, stream>>>(x, xt);
    k_wtt<<<98, 256, 0, stream>>>(Wt, wtt);
    k1_mfma<<<dim3(64, 7), 256, 0, stream>>>(x, wtt, pb);
    k2_attn<<<BL, 256, 0, stream>>>(pb, bh, Wa, ba, ab);
    k3_mfma<<<dim3(49, 4, 8), 256, 0, stream>>>(xt, ab, out);
}